// Round 1
// baseline (361.047 us; speedup 1.0000x reference)
//
#include <hip/hip_runtime.h>
#include <math.h>

#define TLEN  8192
#define BROWS 4096
#define GAMMA 0.99f
#define EPSN  1e-9

// ---------------------------------------------------------------------------
// K1: per-row reverse scan via affine-composition block scan.
// Block = 256 threads = one row. Thread t owns elements [t*32, t*32+32).
// Local chunk scan gives A_j (local return, zero carry) and P_j (coef product
// from j to chunk end). Carry into each chunk via wave shuffle suffix-scan of
// affine maps + LDS combine across the 4 waves. Fixup: ret = A + P*carry.
// Also emits per-row sum (double) and 1/(std_ddof1 + eps).
// ---------------------------------------------------------------------------
__global__ __launch_bounds__(256) void er_scan(const float* __restrict__ rew,
                                               const float* __restrict__ don,
                                               float* __restrict__ out,
                                               double* __restrict__ rowSum,
                                               float* __restrict__ rowInv) {
  const int row = blockIdx.x;
  const int tid = threadIdx.x;
  const size_t base = (size_t)row * TLEN + (size_t)tid * 32;

  float4 rv[8], dv[8];
  float* rw = (float*)rv;   // rw[j] will become A_j after local scan
  float* dn = (float*)dv;   // dn[j] will become P_j after local scan

  const float4* r4 = (const float4*)(rew + base);
  const float4* d4 = (const float4*)(don + base);
#pragma unroll
  for (int k = 0; k < 8; ++k) rv[k] = r4[k];
#pragma unroll
  for (int k = 0; k < 8; ++k) dv[k] = d4[k];

  // local reverse scan (right-to-left within chunk)
  float A = 0.f, P = 1.f;
#pragma unroll
  for (int j = 31; j >= 0; --j) {
    const float c = GAMMA - GAMMA * dn[j];   // exact: done is 0.0 or 1.0
    A = fmaf(c, A, rw[j]);
    P = P * c;
    rw[j] = A;
    dn[j] = P;
  }

  // wave-level inclusive suffix scan of affine maps (A,P); composition:
  // (T_i o T_{i+d})(x) = A_i + P_i*(A' + P'*x)
  const int lane = tid & 63;
  const int wv   = tid >> 6;
  float sA = A, sP = P;
#pragma unroll
  for (int d = 1; d < 64; d <<= 1) {
    const float tA = __shfl_down(sA, d);
    const float tP = __shfl_down(sP, d);
    if (lane + d < 64) { sA = fmaf(sP, tA, sA); sP *= tP; }
  }

  __shared__ float  wgA[4], wgP[4];
  __shared__ double red[8];
  if (lane == 0) { wgA[wv] = sA; wgP[wv] = sP; }
  __syncthreads();

  // carry entering this wave = (T_{wv+1} o ... o T_3)(0), rightmost applied first
  float wc = 0.f;
  for (int j = 3; j > wv; --j) wc = fmaf(wgP[j], wc, wgA[j]);

  // exclusive suffix within wave (composite of lanes lane+1..63)
  float eA = __shfl_down(sA, 1);
  float eP = __shfl_down(sP, 1);
  if (lane == 63) { eA = 0.f; eP = 1.f; }
  const float carry = fmaf(eP, wc, eA);

  // fixup + stats; reuse rv[] as the output values
  float fsum = 0.f, fsq = 0.f;
#pragma unroll
  for (int j = 0; j < 32; ++j) {
    const float r = fmaf(dn[j], carry, rw[j]);
    rw[j] = r;
    fsum += r;
    fsq  = fmaf(r, r, fsq);
  }
  float4* o4 = (float4*)(out + base);
#pragma unroll
  for (int k = 0; k < 8; ++k) o4[k] = rv[k];

  // block reduction in double for row stats
  double ds = (double)fsum, dq = (double)fsq;
#pragma unroll
  for (int d = 32; d >= 1; d >>= 1) {
    ds += __shfl_down(ds, d);
    dq += __shfl_down(dq, d);
  }
  if (lane == 0) { red[wv] = ds; red[4 + wv] = dq; }
  __syncthreads();
  if (tid == 0) {
    const double s = red[0] + red[1] + red[2] + red[3];
    const double q = red[4] + red[5] + red[6] + red[7];
    rowSum[row] = s;
    double var = (q - s * s / (double)TLEN) / (double)(TLEN - 1);
    if (var < 0.0) var = 0.0;
    rowInv[row] = (float)(1.0 / (sqrt(var) + EPSN));
  }
}

// ---------------------------------------------------------------------------
// K2: reduce 4096 per-row sums -> global mean (single block)
// ---------------------------------------------------------------------------
__global__ __launch_bounds__(256) void er_mean(const double* __restrict__ rowSum,
                                               float* __restrict__ meanPtr) {
  const int tid = threadIdx.x;
  double s = 0.0;
  for (int i = tid; i < BROWS; i += 256) s += rowSum[i];
#pragma unroll
  for (int d = 32; d >= 1; d >>= 1) s += __shfl_down(s, d);
  __shared__ double red[4];
  const int lane = tid & 63, wv = tid >> 6;
  if (lane == 0) red[wv] = s;
  __syncthreads();
  if (tid == 0) {
    const double t = red[0] + red[1] + red[2] + red[3];
    *meanPtr = (float)(t / ((double)BROWS * (double)TLEN));
  }
}

// ---------------------------------------------------------------------------
// K3: out = (out - mean) * invstd[row]; block = one row, fully coalesced
// ---------------------------------------------------------------------------
__global__ __launch_bounds__(256) void er_norm(float* __restrict__ out,
                                               const float* __restrict__ rowInv,
                                               const float* __restrict__ meanPtr) {
  const int row = blockIdx.x;
  const float mean = *meanPtr;
  const float inv  = rowInv[row];
  float4* o4 = (float4*)(out + (size_t)row * TLEN);
#pragma unroll
  for (int i = threadIdx.x; i < TLEN / 4; i += 256) {
    float4 v = o4[i];
    v.x = (v.x - mean) * inv;
    v.y = (v.y - mean) * inv;
    v.z = (v.z - mean) * inv;
    v.w = (v.w - mean) * inv;
    o4[i] = v;
  }
}

extern "C" void kernel_launch(void* const* d_in, const int* in_sizes, int n_in,
                              void* d_out, int out_size, void* d_ws, size_t ws_size,
                              hipStream_t stream) {
  const float* rew = (const float*)d_in[0];
  const float* don = (const float*)d_in[1];
  float* out = (float*)d_out;

  double* rowSum  = (double*)d_ws;                              // 32768 B
  float*  rowInv  = (float*)((char*)d_ws + BROWS * 8);          // 16384 B
  float*  meanPtr = (float*)((char*)d_ws + BROWS * 8 + BROWS * 4); // 4 B

  er_scan<<<BROWS, 256, 0, stream>>>(rew, don, out, rowSum, rowInv);
  er_mean<<<1, 256, 0, stream>>>(rowSum, meanPtr);
  er_norm<<<BROWS, 256, 0, stream>>>(out, rowInv, meanPtr);
}

// Round 2
// 353.208 us; speedup vs baseline: 1.0222x; 1.0222x over previous
//
#include <hip/hip_runtime.h>
#include <math.h>

#define TLEN   8192
#define BROWS  4096
#define NT     256
#define TILE   2048
#define CHUNK  8          /* TILE / NT */
#define NTILES (TLEN / TILE)
#define GAMMA  0.99f
#define EPSN   1e-9

// LDS word index with +1 pad word per 8 elements: chunk of thread t occupies
// consecutive words [9t, 9t+8) -> scalar reads are 2-way bank aliased (free).
__device__ __forceinline__ void stash(float* lds, int e0, float4 v) {
  const int w = e0 + (e0 >> 3);   // float4 never crosses a pad (e0 % 4 == 0)
  lds[w + 0] = v.x;
  lds[w + 1] = v.y;
  lds[w + 2] = v.z;
  lds[w + 3] = v.w;
}

// ---------------------------------------------------------------------------
// K1: one row per block. Row processed in 4 tiles of 2048, right-to-left;
// the affine composite of each tile is applied to the running scalar carry.
// Global loads fully coalesced float4 -> LDS (padded) -> 8-elem register
// chunks. Register prefetch of next tile overlaps HBM latency with the scan.
// Emits per-row sum (double) and 1/(std_ddof1+eps).
// ---------------------------------------------------------------------------
__global__ __launch_bounds__(NT) void er_scan(const float* __restrict__ rew,
                                              const float* __restrict__ don,
                                              float* __restrict__ out,
                                              double* __restrict__ rowSum,
                                              float* __restrict__ rowInv) {
  __shared__ float  ldsR[TILE + TILE / 8];
  __shared__ float  ldsD[TILE + TILE / 8];
  __shared__ float  wgA[4], wgP[4];
  __shared__ double red[8];

  const int row  = blockIdx.x;
  const int tid  = threadIdx.x;
  const int lane = tid & 63;
  const int wv   = tid >> 6;
  const size_t rbase = (size_t)row * TLEN;

  const float4* gr = (const float4*)(rew + rbase);
  const float4* gd = (const float4*)(don + rbase);

  float4 pr0, pr1, pd0, pd1;
  {
    const int f = (NTILES - 1) * (TILE / 4);
    pr0 = gr[f + tid];      pr1 = gr[f + NT + tid];
    pd0 = gd[f + tid];      pd1 = gd[f + NT + tid];
  }
  stash(ldsR, 4 * tid, pr0);  stash(ldsR, 1024 + 4 * tid, pr1);
  stash(ldsD, 4 * tid, pd0);  stash(ldsD, 1024 + 4 * tid, pd1);
  __syncthreads();

  double accS = 0.0, accQ = 0.0;
  float  tc = 0.f;   // carry entering the current tile from the right

  for (int k = NTILES - 1; k >= 0; --k) {
    const bool more = (k > 0);
    if (more) {
      const int f = (k - 1) * (TILE / 4);
      pr0 = gr[f + tid];    pr1 = gr[f + NT + tid];
      pd0 = gd[f + tid];    pd1 = gd[f + NT + tid];
    }

    // --- read own 8-element chunk from LDS (2-way bank alias: free) ---
    float rv[CHUNK], cv[CHUNK];
    const int wbase = 9 * tid;
#pragma unroll
    for (int j = 0; j < CHUNK; ++j) rv[j] = ldsR[wbase + j];
#pragma unroll
    for (int j = 0; j < CHUNK; ++j) cv[j] = GAMMA - GAMMA * ldsD[wbase + j];

    // --- local suffix scan of affine maps T_j(x) = rv + cv*x ---
    float A = 0.f, P = 1.f;
#pragma unroll
    for (int j = CHUNK - 1; j >= 0; --j) {
      A = fmaf(cv[j], A, rv[j]);
      P *= cv[j];
      rv[j] = A;   // A_{[j, chunk end)}
      cv[j] = P;   // P_{[j, chunk end)}
    }

    // --- wave inclusive suffix scan of (A,P) composites ---
    float sA = A, sP = P;
#pragma unroll
    for (int d = 1; d < 64; d <<= 1) {
      const float tA = __shfl_down(sA, d);
      const float tP = __shfl_down(sP, d);
      if (lane + d < 64) { sA = fmaf(sP, tA, sA); sP *= tP; }
    }
    if (lane == 0) { wgA[wv] = sA; wgP[wv] = sP; }
    __syncthreads();

    // carry entering this wave = waves (wv,3] composed, applied to tc
    float wc = tc;
#pragma unroll
    for (int j = 3; j >= 1; --j) {
      const float nw = fmaf(wgP[j], wc, wgA[j]);
      wc = (j > wv) ? nw : wc;
    }
    // next tile's carry = all 4 waves composed, applied to tc
    float tcn = tc;
#pragma unroll
    for (int j = 3; j >= 0; --j) tcn = fmaf(wgP[j], tcn, wgA[j]);

    // exclusive within wave (lanes above), then apply wave carry
    float eA = __shfl_down(sA, 1);
    float eP = __shfl_down(sP, 1);
    if (lane == 63) { eA = 0.f; eP = 1.f; }
    const float carry = fmaf(eP, wc, eA);

    // overwrite LDS with prefetched next tile (safe: all reads were pre-barrier)
    if (more) {
      stash(ldsR, 4 * tid, pr0);  stash(ldsR, 1024 + 4 * tid, pr1);
      stash(ldsD, 4 * tid, pd0);  stash(ldsD, 1024 + 4 * tid, pd1);
    }

    // --- fixup, store, stats ---
    float fsum = 0.f, fsq = 0.f;
    float o[CHUNK];
#pragma unroll
    for (int j = 0; j < CHUNK; ++j) {
      const float r = fmaf(cv[j], carry, rv[j]);
      o[j] = r;
      fsum += r;
      fsq  = fmaf(r, r, fsq);
    }
    float4* go = (float4*)(out + rbase + (size_t)k * TILE + (size_t)tid * CHUNK);
    go[0] = make_float4(o[0], o[1], o[2], o[3]);
    go[1] = make_float4(o[4], o[5], o[6], o[7]);
    accS += (double)fsum;
    accQ += (double)fsq;
    tc = tcn;

    if (more) __syncthreads();
  }

  // --- block reduction (double) for row stats ---
  double ds = accS, dq = accQ;
#pragma unroll
  for (int d = 32; d >= 1; d >>= 1) {
    ds += __shfl_down(ds, d);
    dq += __shfl_down(dq, d);
  }
  if (lane == 0) { red[wv] = ds; red[4 + wv] = dq; }
  __syncthreads();
  if (tid == 0) {
    const double s = red[0] + red[1] + red[2] + red[3];
    const double q = red[4] + red[5] + red[6] + red[7];
    rowSum[row] = s;
    double var = (q - s * s / (double)TLEN) / (double)(TLEN - 1);
    if (var < 0.0) var = 0.0;
    rowInv[row] = (float)(1.0 / (sqrt(var) + EPSN));
  }
}

// ---------------------------------------------------------------------------
// K2: reduce 4096 per-row sums -> global mean (single block)
// ---------------------------------------------------------------------------
__global__ __launch_bounds__(256) void er_mean(const double* __restrict__ rowSum,
                                               float* __restrict__ meanPtr) {
  const int tid = threadIdx.x;
  double s = 0.0;
  for (int i = tid; i < BROWS; i += 256) s += rowSum[i];
#pragma unroll
  for (int d = 32; d >= 1; d >>= 1) s += __shfl_down(s, d);
  __shared__ double red[4];
  const int lane = tid & 63, wv = tid >> 6;
  if (lane == 0) red[wv] = s;
  __syncthreads();
  if (tid == 0) {
    const double t = red[0] + red[1] + red[2] + red[3];
    *meanPtr = (float)(t / ((double)BROWS * (double)TLEN));
  }
}

// ---------------------------------------------------------------------------
// K3: out = (out - mean) * invstd[row]; block = one row, fully coalesced
// ---------------------------------------------------------------------------
__global__ __launch_bounds__(256) void er_norm(float* __restrict__ out,
                                               const float* __restrict__ rowInv,
                                               const float* __restrict__ meanPtr) {
  const int row = blockIdx.x;
  const float mean = *meanPtr;
  const float inv  = rowInv[row];
  float4* o4 = (float4*)(out + (size_t)row * TLEN);
#pragma unroll
  for (int i = threadIdx.x; i < TLEN / 4; i += 256) {
    float4 v = o4[i];
    v.x = (v.x - mean) * inv;
    v.y = (v.y - mean) * inv;
    v.z = (v.z - mean) * inv;
    v.w = (v.w - mean) * inv;
    o4[i] = v;
  }
}

extern "C" void kernel_launch(void* const* d_in, const int* in_sizes, int n_in,
                              void* d_out, int out_size, void* d_ws, size_t ws_size,
                              hipStream_t stream) {
  const float* rew = (const float*)d_in[0];
  const float* don = (const float*)d_in[1];
  float* out = (float*)d_out;

  double* rowSum  = (double*)d_ws;
  float*  rowInv  = (float*)((char*)d_ws + BROWS * 8);
  float*  meanPtr = (float*)((char*)d_ws + BROWS * 8 + BROWS * 4);

  er_scan<<<BROWS, NT, 0, stream>>>(rew, don, out, rowSum, rowInv);
  er_mean<<<1, 256, 0, stream>>>(rowSum, meanPtr);
  er_norm<<<BROWS, 256, 0, stream>>>(out, rowInv, meanPtr);
}